// Round 13
// baseline (509.816 us; speedup 1.0000x reference)
//
#include <hip/hip_runtime.h>
#include <cstdint>

// ---------- types ----------
typedef float f32x4 __attribute__((ext_vector_type(4)));
typedef __bf16 bf16x8 __attribute__((ext_vector_type(8)));

#define AS1 __attribute__((address_space(1)))
#define AS3 __attribute__((address_space(3)))

__device__ __forceinline__ void gld_lds16(const void* g, void* l) {
    __builtin_amdgcn_global_load_lds((const AS1 void*)g, (AS3 void*)l, 16, 0, 0);
}

__device__ __forceinline__ unsigned short f2bf(float f) {  // RNE f32->bf16
    unsigned u = __builtin_bit_cast(unsigned, f);
    u = u + 0x7fffu + ((u >> 16) & 1u);
    return (unsigned short)(u >> 16);
}
__device__ __forceinline__ float bf2f(unsigned short h) {
    unsigned u = ((unsigned)h) << 16;
    return __builtin_bit_cast(float, u);
}

__device__ __forceinline__ void bar() {
    asm volatile("" ::: "memory");
    __builtin_amdgcn_s_barrier();
    asm volatile("" ::: "memory");
}

#define WAITVM(n) asm volatile("s_waitcnt vmcnt(" #n ")" ::: "memory")
#define LGKM0     asm volatile("s_waitcnt lgkmcnt(0)" ::: "memory")
#define SCHED0    __builtin_amdgcn_sched_barrier(0)

__device__ __forceinline__ float gelu_f(float t) {
    return 0.5f * t * (1.0f + erff(t * 0.70710678118654752f));
}

// ---------- PER-WAVE-PRIVATE zero-barrier GEMM: C = A @ B^T ----------------
// Block 256x128 (8 waves, 4M x 2N), per-wave 64x64 output, BK=32.
// Each wave owns a PRIVATE 16 KB LDS ring (2 bufs x (A 4KB + B 4KB)); stages
// its own tiles via global_load_lds (dest wave-uniform => private), self-syncs
// with per-wave FIFO vmcnt. NO s_barrier anywhere in the kernel.
// Rationale [R8/R9 probes]: identical per-wave instruction stream with no
// cross-wave sync ran 1260 TF (stages, no sync) vs ~650 TF for every shared-
// LDS schedule tried (R2-R12). This makes the probe structure race-free:
//   order per tile = vmcnt(8) [tile t landed] -> 8 ds_read -> lgkmcnt(0)
//   -> stage(t+2) into the just-read buffer (reads drained => WAR-safe)
//   -> 16 MFMA.  Issue-to-wait distance ~1.5 tiles covers L2-warm latency.
// Swizzle identical to R9-verified (0 bank conflicts).
// MODE 1: C f32 = acc+add; 2: C bf16 = gelu(acc+bias); 3: f32 acc+bias+add
template<int MODE>
__global__ __launch_bounds__(512, 1) void gemm_pw(
    const unsigned short* __restrict__ A, long lda, long sAb,
    const unsigned short* __restrict__ B, long ldb, long sBb,
    void* C, long ldc, long sCb,
    const float* add, long ldadd, long sAddb,
    const float* __restrict__ bias, int K)
{
    __shared__ char sm[8 * 16384];          // 128 KB: 8 waves x private 16 KB
    const int tid = threadIdx.x, lane = tid & 63, wid = tid >> 6;
    const int wr = wid >> 1, wc = wid & 1;  // 4M x 2N wave grid, 64x64 each

    const long zb = blockIdx.z;
    // m204 bijective XCD swizzle
    const int nwg  = gridDim.x * gridDim.y;
    const int orig = blockIdx.y * gridDim.x + blockIdx.x;
    const int q8 = nwg >> 3, r8 = nwg & 7;
    const int xcd = orig & 7;
    const int wg  = (xcd < r8 ? xcd * (q8 + 1) : r8 * (q8 + 1) + (xcd - r8) * q8) + (orig >> 3);
    const int bx = wg % gridDim.x, by = wg / gridDim.x;

    // this wave's 64 A-rows and 64 B-rows
    const char* Ab = (const char*)(A + zb * sAb + ((long)by * 256 + wr * 64) * lda);
    const char* Bb = (const char*)(B + zb * sBb + ((long)bx * 128 + wc * 64) * ldb);
    const long ldaB = lda * 2, ldbB = ldb * 2;
    char* mybuf = sm + wid * 16384;

    // stage one K-tile (A 64x64B + B 64x64B) into private ring buffer b.
    // 8 gld issues; LDS linear row-major; global source chunk pre-swizzled
    // by f(row)=(row>>1)&3 (row = i*16 + lane>>2  =>  f = (lane>>3)&3).
    const long gsw = (long)(((lane & 3) ^ ((lane >> 3) & 3)) << 4);
    auto stage = [&](int kt, int b) {
        char* d = mybuf + b * 8192;
        const long kb = (long)kt * 64 + gsw;
#pragma unroll
        for (int i = 0; i < 4; ++i) {
            const int r = i * 16 + (lane >> 2);
            gld_lds16(Ab + (long)r * ldaB + kb, d + i * 1024);
            gld_lds16(Bb + (long)r * ldbB + kb, d + 4096 + i * 1024);
        }
    };

    f32x4 acc[4][4] = {};
    const int NT = K / 32;
    const int cc = ((lane >> 4) ^ ((lane >> 1) & 3)) << 4;   // frag k-chunk

    stage(0, 0); stage(1, 1);               // 16 loads in flight, no barrier

#pragma unroll 1
    for (int t = 0; t < NT; ++t) {
        if (t + 1 < NT) WAITVM(8); else WAITVM(0);   // tile t landed (FIFO)
        const char* bufp = mybuf + (t & 1) * 8192;
        bf16x8 af[4], bfr[4];
#pragma unroll
        for (int m = 0; m < 4; ++m) {
            const int R = m * 16 + (lane & 15);
            af[m] = *(const bf16x8*)(bufp + R * 64 + cc);
        }
#pragma unroll
        for (int n = 0; n < 4; ++n) {
            const int R = n * 16 + (lane & 15);
            bfr[n] = *(const bf16x8*)(bufp + 4096 + R * 64 + cc);
        }
        LGKM0; SCHED0;                      // my reads drained -> WAR-safe
        if (t + 2 < NT) stage(t + 2, t & 1);// overwrite just-read buffer
#pragma unroll
        for (int m = 0; m < 4; ++m)
#pragma unroll
            for (int n = 0; n < 4; ++n)
                acc[m][n] = __builtin_amdgcn_mfma_f32_16x16x32_bf16(
                    af[m], bfr[n], acc[m][n], 0, 0, 0);
    }

    // epilogue: C/D layout col=lane&15, row=(lane>>4)*4+j
    const long row0 = (long)by * 256 + wr * 64 + (lane >> 4) * 4;
    const long col0 = (long)bx * 128 + wc * 64 + (lane & 15);
#pragma unroll
    for (int m = 0; m < 4; ++m)
#pragma unroll
        for (int n = 0; n < 4; ++n)
#pragma unroll
            for (int j = 0; j < 4; ++j) {
                const long r = row0 + m * 16 + j;
                const long c = col0 + n * 16;
                const float v = acc[m][n][j];
                if (MODE == 1) {
                    ((float*)C)[zb * sCb + r * ldc + c] = v + add[zb * sAddb + r * ldadd + c];
                } else if (MODE == 2) {
                    ((unsigned short*)C)[zb * sCb + r * ldc + c] = f2bf(gelu_f(v + bias[c]));
                } else {
                    ((float*)C)[zb * sCb + r * ldc + c] = v + bias[c] + add[zb * sAddb + r * ldadd + c];
                }
            }
}

// ---------- 128x128 3-ring minimal-sync GEMM (R11 core) — S-GEMM only ------
// TRI=1: symmetric C (A==B), lower-triangle tiles + coalesced mirror store.
template<int MODE, int TRI>
__global__ __launch_bounds__(256, 3) void gemm128(
    const unsigned short* __restrict__ A, long lda, long sAb,
    const unsigned short* __restrict__ B, long ldb, long sBb,
    void* C, long ldc, long sCb,
    const float* add, long ldadd, long sAddb,
    const float* __restrict__ bias, int K)
{
    constexpr int ABUF = 128 * 64;
    constexpr int BUF  = 2 * ABUF;
    __shared__ char sm[3 * BUF];
    const int tid = threadIdx.x, lane = tid & 63, wid = tid >> 6;
    const int wr = wid >> 1, wc = wid & 1;

    const long zb = blockIdx.z;
    const int nwg  = gridDim.x * gridDim.y;
    const int orig = blockIdx.y * gridDim.x + blockIdx.x;
    const int q8 = nwg >> 3, r8 = nwg & 7;
    const int xcd = orig & 7;
    const int wg  = (xcd < r8 ? xcd * (q8 + 1) : r8 * (q8 + 1) + (xcd - r8) * q8) + (orig >> 3);
    int bx, by;
    if constexpr (TRI == 1) {
        int k = 0;
        while (2 * (k + 1) * (k + 1) + (k + 1) <= wg) ++k;
        const int i = wg - (2 * k * k + k);
        const int R = 2 * k;
        if (i < 2 * (R + 1)) { by = R + (i & 1); bx = i >> 1; }
        else                 { by = R + 1;      bx = R + 1;  }
    } else {
        bx = wg % gridDim.x; by = wg / gridDim.x;
    }

    const char* Ab = (const char*)(A + zb * sAb + (long)by * 128 * lda);
    const char* Bb = (const char*)(B + zb * sBb + (long)bx * 128 * ldb);
    const long ldaB = lda * 2, ldbB = ldb * 2;

    const long gsw = (long)(((tid & 3) ^ ((tid >> 3) & 3)) << 4);
    auto stage = [&](int kt, int b) {
#pragma unroll
        for (int i = 0; i < 2; ++i) {
            const int r = i * 64 + (tid >> 2);
            gld_lds16(Ab + (long)r * ldaB + (long)kt * 64 + gsw,
                      sm + b * BUF + i * 4096 + wid * 1024);
            gld_lds16(Bb + (long)r * ldbB + (long)kt * 64 + gsw,
                      sm + b * BUF + ABUF + i * 4096 + wid * 1024);
        }
    };

    f32x4 acc[4][4] = {};
    const int NT = K / 32;
    const int cc = ((lane >> 4) ^ ((lane >> 1) & 3)) << 4;

    stage(0, 0); stage(1, 1);
    WAITVM(4);
    bar();

#pragma unroll 1
    for (int t = 0; t < NT; ++t) {
        const char* bufp = sm + (t % 3) * BUF;
        bf16x8 af[4], bfr[4];
#pragma unroll
        for (int m = 0; m < 4; ++m) {
            const int R = wr * 64 + m * 16 + (lane & 15);
            af[m] = *(const bf16x8*)(bufp + R * 64 + cc);
        }
#pragma unroll
        for (int n = 0; n < 4; ++n) {
            const int R = wc * 64 + n * 16 + (lane & 15);
            bfr[n] = *(const bf16x8*)(bufp + ABUF + R * 64 + cc);
        }
        if (t + 2 < NT) stage(t + 2, (t + 2) % 3);
        LGKM0; SCHED0;
#pragma unroll
        for (int m = 0; m < 4; ++m)
#pragma unroll
            for (int n = 0; n < 4; ++n)
                acc[m][n] = __builtin_amdgcn_mfma_f32_16x16x32_bf16(
                    af[m], bfr[n], acc[m][n], 0, 0, 0);
        if (t + 1 < NT) {
            if (t + 2 < NT) WAITVM(4); else WAITVM(0);
            bar();
        }
    }

    const long row0 = (long)by * 128 + wr * 64 + (lane >> 4) * 4;
    const long col0 = (long)bx * 128 + wc * 64 + (lane & 15);
#pragma unroll
    for (int m = 0; m < 4; ++m)
#pragma unroll
        for (int n = 0; n < 4; ++n)
#pragma unroll
            for (int j = 0; j < 4; ++j) {
                const long r = row0 + m * 16 + j;
                const long c = col0 + n * 16;
                const float v = acc[m][n][j];
                if (MODE == 0) {
                    ((float*)C)[zb * sCb + r * ldc + c] = v;
                } else if (MODE == 1) {
                    ((float*)C)[zb * sCb + r * ldc + c] = v + add[zb * sAddb + r * ldadd + c];
                } else if (MODE == 2) {
                    ((unsigned short*)C)[zb * sCb + r * ldc + c] = f2bf(gelu_f(v + bias[c]));
                } else {
                    ((float*)C)[zb * sCb + r * ldc + c] = v + bias[c] + add[zb * sAddb + r * ldadd + c];
                }
            }
    if constexpr (TRI == 1) {
        if (by != bx) {
#pragma unroll
            for (int m = 0; m < 4; ++m)
#pragma unroll
                for (int n = 0; n < 4; ++n) {
                    float* dst = (float*)C + zb * sCb + (col0 + n * 16) * ldc + (row0 + m * 16);
                    *(float4*)dst = (float4){acc[m][n][0], acc[m][n][1], acc[m][n][2], acc[m][n][3]};
                }
        }
    }
}

// ---------- LayerNorm ----------
__global__ __launch_bounds__(256) void ln_kernel(
    const float* __restrict__ x, const float* __restrict__ gamma, const float* __restrict__ beta,
    unsigned short* __restrict__ out, int ldout, float* qout, int pad)
{
    const int tid = threadIdx.x;
    const long row = blockIdx.x;
    float4 v = ((const float4*)(x + row * 1024))[tid];
    float s = v.x + v.y + v.z + v.w;
    float s2 = v.x * v.x + v.y * v.y + v.z * v.z + v.w * v.w;
#pragma unroll
    for (int off = 32; off; off >>= 1) {
        s  += __shfl_down(s, off);
        s2 += __shfl_down(s2, off);
    }
    __shared__ float red[12];
    const int lane = tid & 63, wid = tid >> 6;
    if (lane == 0) { red[wid] = s; red[4 + wid] = s2; }
    __syncthreads();
    s  = red[0] + red[1] + red[2] + red[3];
    s2 = red[4] + red[5] + red[6] + red[7];
    const float mu = s * (1.0f / 1024.0f);
    const float var = s2 * (1.0f / 1024.0f) - mu * mu;
    const float rs = rsqrtf(var + 1e-5f);
    const float4 g = ((const float4*)gamma)[tid];
    const float4 b = ((const float4*)beta)[tid];
    unsigned short o0 = f2bf((v.x - mu) * rs * g.x + b.x);
    unsigned short o1 = f2bf((v.y - mu) * rs * g.y + b.y);
    unsigned short o2 = f2bf((v.z - mu) * rs * g.z + b.z);
    unsigned short o3 = f2bf((v.w - mu) * rs * g.w + b.w);
    ushort4 ov; ov.x = o0; ov.y = o1; ov.z = o2; ov.w = o3;
    ((ushort4*)(out + row * (long)ldout))[tid] = ov;
    if (pad && tid < 32) out[row * (long)ldout + 1056 + tid] = 0;
    if (qout) {
        float y0 = bf2f(o0), y1 = bf2f(o1), y2 = bf2f(o2), y3 = bf2f(o3);
        float sq = y0 * y0 + y1 * y1 + y2 * y2 + y3 * y3;
#pragma unroll
        for (int off = 32; off; off >>= 1) sq += __shfl_down(sq, off);
        if (lane == 0) red[8 + wid] = sq;
        __syncthreads();
        if (tid == 0) qout[row] = red[8] + red[9] + red[10] + red[11];
    }
}

// ---------- u = hn @ L ----------
__global__ __launch_bounds__(256) void u_kernel(
    unsigned short* __restrict__ z, const float* __restrict__ L, float* __restrict__ q)
{
    const int tid = threadIdx.x;
    const long row = blockIdx.x;
    __shared__ float hn[1024];
    __shared__ float part[8][32];
    ushort4 uv = ((const ushort4*)(z + row * 1088))[tid];
    hn[tid * 4 + 0] = bf2f(uv.x);
    hn[tid * 4 + 1] = bf2f(uv.y);
    hn[tid * 4 + 2] = bf2f(uv.z);
    hn[tid * 4 + 3] = bf2f(uv.w);
    __syncthreads();
    const int j = tid & 31, grp = tid >> 5;
    float acc = 0.f;
    const float* Lp = L + j;
#pragma unroll 4
    for (int d = grp * 128; d < grp * 128 + 128; ++d)
        acc += hn[d] * Lp[(long)d * 32];
    part[grp][j] = acc;
    __syncthreads();
    if (tid < 32) {
        float u = 0.f;
#pragma unroll
        for (int g2 = 0; g2 < 8; ++g2) u += part[g2][tid];
        unsigned short ub = f2bf(u);
        z[row * 1088 + 1024 + tid] = ub;
        float uf = bf2f(ub);
        part[0][tid] = uf * uf;
    }
    __syncthreads();
    if (tid == 0) {
        float sq = 0.f;
#pragma unroll
        for (int t2 = 0; t2 < 32; ++t2) sq += part[0][t2];
        q[row] += sq;
    }
}

// ---------- softmax ----------
__global__ __launch_bounds__(256) void softmax_kernel(
    float* S, const float* qb)
{
    const int tid = threadIdx.x;
    const long i = blockIdx.x, bl = blockIdx.y;
    float* Sr = S + (bl * 2048 + i) * 2048;
    const float* qr = qb + bl * 2048;
    float l[8];
    float mx = -1e30f;
#pragma unroll
    for (int c2 = 0; c2 < 8; ++c2) {
        const int jj = tid + c2 * 256;
        l[c2] = 2.0f * Sr[jj] - qr[jj];
        mx = fmaxf(mx, l[c2]);
    }
#pragma unroll
    for (int off = 32; off; off >>= 1) mx = fmaxf(mx, __shfl_xor(mx, off));
    __shared__ float red[8];
    const int lane = tid & 63, wid = tid >> 6;
    if (lane == 0) red[wid] = mx;
    __syncthreads();
    mx = fmaxf(fmaxf(red[0], red[1]), fmaxf(red[2], red[3]));
    float sum = 0.f;
#pragma unroll
    for (int c2 = 0; c2 < 8; ++c2) { l[c2] = __expf(l[c2] - mx); sum += l[c2]; }
#pragma unroll
    for (int off = 32; off; off >>= 1) sum += __shfl_xor(sum, off);
    if (lane == 0) red[4 + wid] = sum;
    __syncthreads();
    sum = red[4] + red[5] + red[6] + red[7];
    const float inv = 1.0f / sum;
    unsigned short* Pr = (unsigned short*)S + (bl * 2048 + i) * 4096;
#pragma unroll
    for (int c2 = 0; c2 < 8; ++c2)
        Pr[tid + c2 * 256] = f2bf(l[c2] * inv);
}

// ---------- Vt transpose ----------
__global__ __launch_bounds__(256) void transpose_v_kernel(
    const unsigned short* __restrict__ z, unsigned short* __restrict__ Vt, long sVtb)
{
    __shared__ unsigned short t[32][33];
    const int tid = threadIdx.x;
    const int tx = tid & 31, ty = tid >> 5;
    const long b = blockIdx.z;
    const long k0 = (long)blockIdx.x * 32, n0 = (long)blockIdx.y * 32;
#pragma unroll
    for (int r = 0; r < 32; r += 8)
        t[r + ty][tx] = z[(b * 2048 + k0 + r + ty) * 1088 + n0 + tx];
    __syncthreads();
#pragma unroll
    for (int r = 0; r < 32; r += 8)
        Vt[b * sVtb + (n0 + r + ty) * 2048 + k0 + tx] = t[tx][r + ty];
}

// ---------- weight cast-transpose ----------
__global__ __launch_bounds__(256) void cast_transpose_kernel(
    const float* __restrict__ W, unsigned short* __restrict__ Wt, int rows, int cols)
{
    __shared__ float t[32][33];
    const int tid = threadIdx.x;
    const int tx = tid & 31, ty = tid >> 5;
    const long r0 = (long)blockIdx.y * 32, c0 = (long)blockIdx.x * 32;
#pragma unroll
    for (int r = 0; r < 32; r += 8)
        t[r + ty][tx] = W[(r0 + r + ty) * (long)cols + c0 + tx];
    __syncthreads();
#pragma unroll
    for (int r = 0; r < 32; r += 8)
        Wt[(c0 + r + ty) * (long)rows + r0 + tx] = f2bf(t[tx][r + ty]);
}

// ---------- host ----------
extern "C" void kernel_launch(void* const* d_in, const int* in_sizes, int n_in,
                              void* d_out, int out_size, void* d_ws, size_t ws_size,
                              hipStream_t stream)
{
    const float* x   = (const float*)d_in[0];
    const float* L   = (const float*)d_in[1];
    const float* W1  = (const float*)d_in[2];
    const float* b1  = (const float*)d_in[3];
    const float* W2  = (const float*)d_in[4];
    const float* b2  = (const float*)d_in[5];
    const float* g1  = (const float*)d_in[6];
    const float* be1 = (const float*)d_in[7];
    const float* g2  = (const float*)d_in[8];
    const float* be2 = (const float*)d_in[9];
    float* out = (float*)d_out;
    unsigned short* z = (unsigned short*)d_out;

    char* wsp = (char*)d_ws;
    float* q = (float*)wsp;
    char* pool = wsp + 32768;
    unsigned short* Vt   = (unsigned short*)pool;
    float*          Smat = (float*)(pool + 16777216);
    unsigned short* W1t = (unsigned short*)pool;
    unsigned short* W2t = (unsigned short*)(pool + 8388608);
    unsigned short* hm  = (unsigned short*)(pool + 16777216);
    unsigned short* hid = (unsigned short*)(pool + 33554432);
    const bool fullMLP = ws_size >= (size_t)32768 + 100663296 + 65536;

    ln_kernel<<<8192, 256, 0, stream>>>(x, g1, be1, z, 1088, q, 1);
    u_kernel<<<8192, 256, 0, stream>>>(z, L, q);

    transpose_v_kernel<<<dim3(64, 32, 4), 256, 0, stream>>>(z, Vt, (long)1024 * 2048);
    gemm128<0, 1><<<dim3(136, 1, 4), 256, 0, stream>>>(
        z, 1088, (long)2048 * 1088,
        z, 1088, (long)2048 * 1088,
        Smat, 2048, (long)2048 * 2048,
        nullptr, 0, 0, nullptr, 1088);
    softmax_kernel<<<dim3(2048, 4), 256, 0, stream>>>(Smat, q);
    // PV on the per-wave zero-barrier core: block 256x128, grid 8x8x4
    gemm_pw<1><<<dim3(8, 8, 4), 512, 0, stream>>>(
        (const unsigned short*)Smat, 4096, (long)2048 * 4096,
        Vt, 2048, (long)1024 * 2048,
        out, 1024, (long)2048 * 1024,
        x, 1024, (long)2048 * 1024,
        nullptr, 2048);

    cast_transpose_kernel<<<dim3(128, 32), 256, 0, stream>>>(W1, W1t, 1024, 4096);
    cast_transpose_kernel<<<dim3(32, 128), 256, 0, stream>>>(W2, W2t, 4096, 1024);
    ln_kernel<<<8192, 256, 0, stream>>>(out, g2, be2, hm, 1024, nullptr, 0);
    if (fullMLP) {
        gemm_pw<2><<<dim3(32, 32, 1), 512, 0, stream>>>(
            hm, 1024, 0, W1t, 1024, 0,
            hid, 4096, 0, nullptr, 0, 0, b1, 1024);
        gemm_pw<3><<<dim3(8, 32, 1), 512, 0, stream>>>(
            hid, 4096, 0, W2t, 4096, 0,
            out, 1024, 0, out, 1024, 0, b2, 4096);
    } else {
        for (int c = 0; c < 2; ++c) {
            const unsigned short* hmc = hm + (size_t)c * 4096 * 1024;
            float* oc = out + (size_t)c * 4096 * 1024;
            gemm_pw<2><<<dim3(32, 16, 1), 512, 0, stream>>>(
                hmc, 1024, 0, W1t, 1024, 0,
                hid, 4096, 0, nullptr, 0, 0, b1, 1024);
            gemm_pw<3><<<dim3(8, 16, 1), 512, 0, stream>>>(
                hid, 4096, 0, W2t, 4096, 0,
                oc, 1024, 0, oc, 1024, 0, b2, 4096);
        }
    }
}

// Round 14
// 371.912 us; speedup vs baseline: 1.3708x; 1.3708x over previous
//
#include <hip/hip_runtime.h>
#include <cstdint>

// ---------- types ----------
typedef float f32x4 __attribute__((ext_vector_type(4)));
typedef __bf16 bf16x8 __attribute__((ext_vector_type(8)));

#define AS1 __attribute__((address_space(1)))
#define AS3 __attribute__((address_space(3)))

__device__ __forceinline__ void gld_lds16(const void* g, void* l) {
    __builtin_amdgcn_global_load_lds((const AS1 void*)g, (AS3 void*)l, 16, 0, 0);
}

__device__ __forceinline__ unsigned short f2bf(float f) {  // RNE f32->bf16
    unsigned u = __builtin_bit_cast(unsigned, f);
    u = u + 0x7fffu + ((u >> 16) & 1u);
    return (unsigned short)(u >> 16);
}
__device__ __forceinline__ float bf2f(unsigned short h) {
    unsigned u = ((unsigned)h) << 16;
    return __builtin_bit_cast(float, u);
}

__device__ __forceinline__ void bar() {
    asm volatile("" ::: "memory");
    __builtin_amdgcn_s_barrier();
    asm volatile("" ::: "memory");
}

#define WAITVM(n) asm volatile("s_waitcnt vmcnt(" #n ")" ::: "memory")
#define LGKM0     asm volatile("s_waitcnt lgkmcnt(0)" ::: "memory")
#define SCHED0    __builtin_amdgcn_sched_barrier(0)

// fast GELU (tanh form via exp): |err| < 1e-3 absolute; propagated through
// W2 (K=4096, w~N(0,1/64^2)) adds <0.01 to output — margin is 0.16.
__device__ __forceinline__ float gelu_f(float x) {
    const float t = x * x;
    const float arg = x * (1.5957691216f + 0.0713548162f * t);
    return x / (1.0f + __expf(-arg));
}

// ---------- 128x128 3-ring minimal-sync GEMM (R11 core) --------------------
// BK=32, 4 waves (2x2), 3 x 16KB LDS ring -> 3 blocks/CU.
// TRI=1: symmetric C (A==B): lower-triangle tiles (136) + mirrored store.
//   MODE 0 with TRI writes LOGITS: C = 2*acc - q[col] (q via `add`,
//   batch-stride sAddb); mirror writes 2*acc - q[row].
// BAND>0 (TRI=0): within-XCD band-column-major traversal — wg walks BAND
//   M-rows per N-col, so XCD working set = BAND A-panels + 1 hot B-panel
//   (<= 4MB L2). Fixes MLP1's measured 215MB L2-miss traffic (8.6x unique).
// MODE 0: C f32 = 2*acc - q; 1: acc+add; 2: bf16 gelu(acc+bias);
// MODE 3: f32 acc+bias+add
template<int MODE, int TRI, int BAND>
__global__ __launch_bounds__(256, 3) void gemm128(
    const unsigned short* __restrict__ A, long lda, long sAb,
    const unsigned short* __restrict__ B, long ldb, long sBb,
    void* C, long ldc, long sCb,
    const float* add, long ldadd, long sAddb,
    const float* __restrict__ bias, int K)
{
    constexpr int ABUF = 128 * 64;         // 8 KB
    constexpr int BUF  = 2 * ABUF;         // 16 KB (A + B)
    __shared__ char sm[3 * BUF];           // 48 KB
    const int tid = threadIdx.x, lane = tid & 63, wid = tid >> 6;
    const int wr = wid >> 1, wc = wid & 1;  // 2x2 wave grid, 64x64 each

    const long zb = blockIdx.z;
    // m204 bijective XCD swizzle
    const int nwg  = gridDim.x * gridDim.y;
    const int orig = blockIdx.y * gridDim.x + blockIdx.x;
    const int q8 = nwg >> 3, r8 = nwg & 7;
    const int xcd = orig & 7;
    const int wg  = (xcd < r8 ? xcd * (q8 + 1) : r8 * (q8 + 1) + (xcd - r8) * q8) + (orig >> 3);
    int bx, by;
    if constexpr (TRI == 1) {
        // triangle decode: band k (rows 2k,2k+1), col-major within band
        int k = 0;
        while (2 * (k + 1) * (k + 1) + (k + 1) <= wg) ++k;
        const int i = wg - (2 * k * k + k);
        const int R = 2 * k;
        if (i < 2 * (R + 1)) { by = R + (i & 1); bx = i >> 1; }
        else                 { by = R + 1;      bx = R + 1;  }
    } else if constexpr (BAND > 0) {
        const int bandw = BAND * gridDim.x;
        const int band  = wg / bandw;
        const int r     = wg - band * bandw;
        bx = r / BAND;
        by = band * BAND + (r % BAND);
    } else {
        bx = wg % gridDim.x; by = wg / gridDim.x;
    }

    const char* Ab = (const char*)(A + zb * sAb + (long)by * 128 * lda);
    const char* Bb = (const char*)(B + zb * sBb + (long)bx * 128 * ldb);
    const long ldaB = lda * 2, ldbB = ldb * 2;

    const long gsw = (long)(((tid & 3) ^ ((tid >> 3) & 3)) << 4);
    auto stage = [&](int kt, int b) {
#pragma unroll
        for (int i = 0; i < 2; ++i) {
            const int r = i * 64 + (tid >> 2);
            gld_lds16(Ab + (long)r * ldaB + (long)kt * 64 + gsw,
                      sm + b * BUF + i * 4096 + wid * 1024);
            gld_lds16(Bb + (long)r * ldbB + (long)kt * 64 + gsw,
                      sm + b * BUF + ABUF + i * 4096 + wid * 1024);
        }
    };

    f32x4 acc[4][4] = {};
    const int NT = K / 32;
    const int cc = ((lane >> 4) ^ ((lane >> 1) & 3)) << 4;   // frag k-chunk

    stage(0, 0); stage(1, 1);
    WAITVM(4);
    bar();

#pragma unroll 1
    for (int t = 0; t < NT; ++t) {
        const char* bufp = sm + (t % 3) * BUF;
        bf16x8 af[4], bfr[4];
#pragma unroll
        for (int m = 0; m < 4; ++m) {
            const int R = wr * 64 + m * 16 + (lane & 15);
            af[m] = *(const bf16x8*)(bufp + R * 64 + cc);
        }
#pragma unroll
        for (int n = 0; n < 4; ++n) {
            const int R = wc * 64 + n * 16 + (lane & 15);
            bfr[n] = *(const bf16x8*)(bufp + ABUF + R * 64 + cc);
        }
        if (t + 2 < NT) stage(t + 2, (t + 2) % 3);
        LGKM0; SCHED0;
#pragma unroll
        for (int m = 0; m < 4; ++m)
#pragma unroll
            for (int n = 0; n < 4; ++n)
                acc[m][n] = __builtin_amdgcn_mfma_f32_16x16x32_bf16(
                    af[m], bfr[n], acc[m][n], 0, 0, 0);
        if (t + 1 < NT) {
            if (t + 2 < NT) WAITVM(4); else WAITVM(0);
            bar();
        }
    }

    // epilogue: C/D layout col=lane&15, row=(lane>>4)*4+j
    const long row0 = (long)by * 128 + wr * 64 + (lane >> 4) * 4;
    const long col0 = (long)bx * 128 + wc * 64 + (lane & 15);
#pragma unroll
    for (int m = 0; m < 4; ++m)
#pragma unroll
        for (int n = 0; n < 4; ++n)
#pragma unroll
            for (int j = 0; j < 4; ++j) {
                const long r = row0 + m * 16 + j;
                const long c = col0 + n * 16;
                const float v = acc[m][n][j];
                if (MODE == 0) {
                    // logits: 2*S - q_j (q via add, batch stride sAddb)
                    ((float*)C)[zb * sCb + r * ldc + c] = 2.0f * v - add[zb * sAddb + c];
                } else if (MODE == 1) {
                    ((float*)C)[zb * sCb + r * ldc + c] = v + add[zb * sAddb + r * ldadd + c];
                } else if (MODE == 2) {
                    ((unsigned short*)C)[zb * sCb + r * ldc + c] = f2bf(gelu_f(v + bias[c]));
                } else {
                    ((float*)C)[zb * sCb + r * ldc + c] = v + bias[c] + add[zb * sAddb + r * ldadd + c];
                }
            }
    if constexpr (TRI == 1) {
        if (by != bx) {   // mirror: C[c][r] = 2*S[r][c] - q_r
#pragma unroll
            for (int m = 0; m < 4; ++m) {
                const float4 qv = *(const float4*)(add + zb * sAddb + row0 + m * 16);
#pragma unroll
                for (int n = 0; n < 4; ++n) {
                    float* dst = (float*)C + zb * sCb + (col0 + n * 16) * ldc + (row0 + m * 16);
                    *(float4*)dst = (float4){2.0f * acc[m][n][0] - qv.x,
                                             2.0f * acc[m][n][1] - qv.y,
                                             2.0f * acc[m][n][2] - qv.z,
                                             2.0f * acc[m][n][3] - qv.w};
                }
            }
        }
    }
}

// ---------- LayerNorm ----------
__global__ __launch_bounds__(256) void ln_kernel(
    const float* __restrict__ x, const float* __restrict__ gamma, const float* __restrict__ beta,
    unsigned short* __restrict__ out, int ldout, float* qout, int pad)
{
    const int tid = threadIdx.x;
    const long row = blockIdx.x;
    float4 v = ((const float4*)(x + row * 1024))[tid];
    float s = v.x + v.y + v.z + v.w;
    float s2 = v.x * v.x + v.y * v.y + v.z * v.z + v.w * v.w;
#pragma unroll
    for (int off = 32; off; off >>= 1) {
        s  += __shfl_down(s, off);
        s2 += __shfl_down(s2, off);
    }
    __shared__ float red[12];
    const int lane = tid & 63, wid = tid >> 6;
    if (lane == 0) { red[wid] = s; red[4 + wid] = s2; }
    __syncthreads();
    s  = red[0] + red[1] + red[2] + red[3];
    s2 = red[4] + red[5] + red[6] + red[7];
    const float mu = s * (1.0f / 1024.0f);
    const float var = s2 * (1.0f / 1024.0f) - mu * mu;
    const float rs = rsqrtf(var + 1e-5f);
    const float4 g = ((const float4*)gamma)[tid];
    const float4 b = ((const float4*)beta)[tid];
    unsigned short o0 = f2bf((v.x - mu) * rs * g.x + b.x);
    unsigned short o1 = f2bf((v.y - mu) * rs * g.y + b.y);
    unsigned short o2 = f2bf((v.z - mu) * rs * g.z + b.z);
    unsigned short o3 = f2bf((v.w - mu) * rs * g.w + b.w);
    ushort4 ov; ov.x = o0; ov.y = o1; ov.z = o2; ov.w = o3;
    ((ushort4*)(out + row * (long)ldout))[tid] = ov;
    if (pad && tid < 32) out[row * (long)ldout + 1056 + tid] = 0;
    if (qout) {
        float y0 = bf2f(o0), y1 = bf2f(o1), y2 = bf2f(o2), y3 = bf2f(o3);
        float sq = y0 * y0 + y1 * y1 + y2 * y2 + y3 * y3;
#pragma unroll
        for (int off = 32; off; off >>= 1) sq += __shfl_down(sq, off);
        if (lane == 0) red[8 + wid] = sq;
        __syncthreads();
        if (tid == 0) qout[row] = red[8] + red[9] + red[10] + red[11];
    }
}

// ---------- u = hn @ L ----------
__global__ __launch_bounds__(256) void u_kernel(
    unsigned short* __restrict__ z, const float* __restrict__ L, float* __restrict__ q)
{
    const int tid = threadIdx.x;
    const long row = blockIdx.x;
    __shared__ float hn[1024];
    __shared__ float part[8][32];
    ushort4 uv = ((const ushort4*)(z + row * 1088))[tid];
    hn[tid * 4 + 0] = bf2f(uv.x);
    hn[tid * 4 + 1] = bf2f(uv.y);
    hn[tid * 4 + 2] = bf2f(uv.z);
    hn[tid * 4 + 3] = bf2f(uv.w);
    __syncthreads();
    const int j = tid & 31, grp = tid >> 5;
    float acc = 0.f;
    const float* Lp = L + j;
#pragma unroll 4
    for (int d = grp * 128; d < grp * 128 + 128; ++d)
        acc += hn[d] * Lp[(long)d * 32];
    part[grp][j] = acc;
    __syncthreads();
    if (tid < 32) {
        float u = 0.f;
#pragma unroll
        for (int g2 = 0; g2 < 8; ++g2) u += part[g2][tid];
        unsigned short ub = f2bf(u);
        z[row * 1088 + 1024 + tid] = ub;
        float uf = bf2f(ub);
        part[0][tid] = uf * uf;
    }
    __syncthreads();
    if (tid == 0) {
        float sq = 0.f;
#pragma unroll
        for (int t2 = 0; t2 < 32; ++t2) sq += part[0][t2];
        q[row] += sq;
    }
}

// ---------- softmax over row: logits already in S; write P bf16 in place ---
__global__ __launch_bounds__(256) void softmax_kernel(float* S)
{
    const int tid = threadIdx.x;
    const long i = blockIdx.x, bl = blockIdx.y;
    float* Sr = S + (bl * 2048 + i) * 2048;
    float l[8];
    float mx = -1e30f;
#pragma unroll
    for (int c2 = 0; c2 < 8; ++c2) {
        l[c2] = Sr[tid + c2 * 256];
        mx = fmaxf(mx, l[c2]);
    }
#pragma unroll
    for (int off = 32; off; off >>= 1) mx = fmaxf(mx, __shfl_xor(mx, off));
    __shared__ float red[8];
    const int lane = tid & 63, wid = tid >> 6;
    if (lane == 0) red[wid] = mx;
    __syncthreads();
    mx = fmaxf(fmaxf(red[0], red[1]), fmaxf(red[2], red[3]));
    float sum = 0.f;
#pragma unroll
    for (int c2 = 0; c2 < 8; ++c2) { l[c2] = __expf(l[c2] - mx); sum += l[c2]; }
#pragma unroll
    for (int off = 32; off; off >>= 1) sum += __shfl_xor(sum, off);
    if (lane == 0) red[4 + wid] = sum;
    __syncthreads();
    sum = red[4] + red[5] + red[6] + red[7];
    const float inv = 1.0f / sum;
    unsigned short* Pr = (unsigned short*)S + (bl * 2048 + i) * 4096;
#pragma unroll
    for (int c2 = 0; c2 < 8; ++c2)
        Pr[tid + c2 * 256] = f2bf(l[c2] * inv);
}

// ---------- Vt transpose ----------
__global__ __launch_bounds__(256) void transpose_v_kernel(
    const unsigned short* __restrict__ z, unsigned short* __restrict__ Vt, long sVtb)
{
    __shared__ unsigned short t[32][33];
    const int tid = threadIdx.x;
    const int tx = tid & 31, ty = tid >> 5;
    const long b = blockIdx.z;
    const long k0 = (long)blockIdx.x * 32, n0 = (long)blockIdx.y * 32;
#pragma unroll
    for (int r = 0; r < 32; r += 8)
        t[r + ty][tx] = z[(b * 2048 + k0 + r + ty) * 1088 + n0 + tx];
    __syncthreads();
#pragma unroll
    for (int r = 0; r < 32; r += 8)
        Vt[b * sVtb + (n0 + r + ty) * 2048 + k0 + tx] = t[tx][r + ty];
}

// ---------- weight cast-transpose ----------
__global__ __launch_bounds__(256) void cast_transpose_kernel(
    const float* __restrict__ W, unsigned short* __restrict__ Wt, int rows, int cols)
{
    __shared__ float t[32][33];
    const int tid = threadIdx.x;
    const int tx = tid & 31, ty = tid >> 5;
    const long r0 = (long)blockIdx.y * 32, c0 = (long)blockIdx.x * 32;
#pragma unroll
    for (int r = 0; r < 32; r += 8)
        t[r + ty][tx] = W[(r0 + r + ty) * (long)cols + c0 + tx];
    __syncthreads();
#pragma unroll
    for (int r = 0; r < 32; r += 8)
        Wt[(c0 + r + ty) * (long)rows + r0 + tx] = f2bf(t[tx][r + ty]);
}

// ---------- host ----------
extern "C" void kernel_launch(void* const* d_in, const int* in_sizes, int n_in,
                              void* d_out, int out_size, void* d_ws, size_t ws_size,
                              hipStream_t stream)
{
    const float* x   = (const float*)d_in[0];
    const float* L   = (const float*)d_in[1];
    const float* W1  = (const float*)d_in[2];
    const float* b1  = (const float*)d_in[3];
    const float* W2  = (const float*)d_in[4];
    const float* b2  = (const float*)d_in[5];
    const float* g1  = (const float*)d_in[6];
    const float* be1 = (const float*)d_in[7];
    const float* g2  = (const float*)d_in[8];
    const float* be2 = (const float*)d_in[9];
    float* out = (float*)d_out;
    unsigned short* z = (unsigned short*)d_out;

    char* wsp = (char*)d_ws;
    float* q = (float*)wsp;
    char* pool = wsp + 32768;
    unsigned short* Vt   = (unsigned short*)pool;
    float*          Smat = (float*)(pool + 16777216);
    unsigned short* W1t = (unsigned short*)pool;
    unsigned short* W2t = (unsigned short*)(pool + 8388608);
    unsigned short* hm  = (unsigned short*)(pool + 16777216);
    unsigned short* hid = (unsigned short*)(pool + 33554432);
    const bool fullMLP = ws_size >= (size_t)32768 + 100663296 + 65536;

    ln_kernel<<<8192, 256, 0, stream>>>(x, g1, be1, z, 1088, q, 1);
    u_kernel<<<8192, 256, 0, stream>>>(z, L, q);

    transpose_v_kernel<<<dim3(64, 32, 4), 256, 0, stream>>>(z, Vt, (long)1024 * 2048);
    // S-logits = 2*z z^T - q_j, lower-triangle tiles + mirror (q via `add`)
    gemm128<0, 1, 0><<<dim3(136, 1, 4), 256, 0, stream>>>(
        z, 1088, (long)2048 * 1088,
        z, 1088, (long)2048 * 1088,
        Smat, 2048, (long)2048 * 2048,
        q, 0, 2048, nullptr, 1088);
    softmax_kernel<<<dim3(2048, 4), 256, 0, stream>>>(Smat);
    gemm128<1, 0, 4><<<dim3(8, 16, 4), 256, 0, stream>>>(
        (const unsigned short*)Smat, 4096, (long)2048 * 4096,
        Vt, 2048, (long)1024 * 2048,
        out, 1024, (long)2048 * 1024,
        x, 1024, (long)2048 * 1024,
        nullptr, 2048);

    cast_transpose_kernel<<<dim3(128, 32), 256, 0, stream>>>(W1, W1t, 1024, 4096);
    cast_transpose_kernel<<<dim3(32, 128), 256, 0, stream>>>(W2, W2t, 4096, 1024);
    ln_kernel<<<8192, 256, 0, stream>>>(out, g2, be2, hm, 1024, nullptr, 0);
    if (fullMLP) {
        gemm128<2, 0, 8><<<dim3(32, 64, 1), 256, 0, stream>>>(
            hm, 1024, 0, W1t, 1024, 0,
            hid, 4096, 0, nullptr, 0, 0, b1, 1024);
        gemm128<3, 0, 2><<<dim3(8, 64, 1), 256, 0, stream>>>(
            hid, 4096, 0, W2t, 4096, 0,
            out, 1024, 0, out, 1024, 0, b2, 4096);
    } else {
        for (int c = 0; c < 2; ++c) {
            const unsigned short* hmc = hm + (size_t)c * 4096 * 1024;
            float* oc = out + (size_t)c * 4096 * 1024;
            gemm128<2, 0, 8><<<dim3(32, 32, 1), 256, 0, stream>>>(
                hmc, 1024, 0, W1t, 1024, 0,
                hid, 4096, 0, nullptr, 0, 0, b1, 1024);
            gemm128<3, 0, 2><<<dim3(8, 32, 1), 256, 0, stream>>>(
                hid, 4096, 0, W2t, 4096, 0,
                oc, 1024, 0, oc, 1024, 0, b2, 4096);
        }
    }
}